// Round 4
// baseline (323.072 us; speedup 1.0000x reference)
//
#include <hip/hip_runtime.h>
#include <hip/hip_bf16.h>
#include <stdint.h>
#include <stddef.h>

typedef __bf16 bf16_t;
typedef __attribute__((ext_vector_type(8))) __bf16 bf16x8;   // 4 VGPRs, MFMA A/B operand
typedef __attribute__((ext_vector_type(4))) float f32x4;     // MFMA C/D

#define MFMA_BF16(a, b, c) __builtin_amdgcn_mfma_f32_16x16x32_bf16((a), (b), (c), 0, 0, 0)

// ---------------- dtype detector -------------------------------------------------
// bf16 N(0,1) data: exp field <= ~0x82. float32 buffer read as uint16: even-index
// elements are mantissa low bits -> exp uniform -> ~45% have exp>=0x8D. Count>16
// over 16384 elements => inputs are float32.
__global__ void detect_dtype(const unsigned short* __restrict__ x, int* __restrict__ flag) {
  __shared__ int cnt;
  if (threadIdx.x == 0) cnt = 0;
  __syncthreads();
  int local = 0;
  for (int i = threadIdx.x; i < 16384; i += 256) {
    const int e = (x[i] >> 7) & 0xFF;
    if (e >= 0x8D) local++;
  }
  atomicAdd(&cnt, local);
  __syncthreads();
  if (threadIdx.x == 0) *flag = (cnt > 16) ? 1 : 0;
}

// ---------------- transpose (any input dtype -> bf16): out[c][r] = in[r][c] ------
__global__ void transpose_any(const void* __restrict__ in, bf16_t* __restrict__ out,
                              int R, int C, const int* __restrict__ flagp) {
  const int isF32 = *flagp;
  __shared__ bf16_t tile[32][33];
  const int tx = threadIdx.x, ty = threadIdx.y;
  const int r0 = blockIdx.y * 32, c0 = blockIdx.x * 32;
#pragma unroll
  for (int i = 0; i < 4; ++i) {
    const size_t idx = (size_t)(r0 + ty + i * 8) * C + (c0 + tx);
    tile[ty + i * 8][tx] = isF32 ? (bf16_t)((const float*)in)[idx]
                                 : ((const bf16_t*)in)[idx];
  }
  __syncthreads();
#pragma unroll
  for (int i = 0; i < 4; ++i)
    out[(size_t)(c0 + ty + i * 8) * R + (r0 + tx)] = tile[tx][ty + i * 8];
}

__device__ __forceinline__ bf16x8 cvt8(const float* f) {
  const float4 a = *(const float4*)f, b = *(const float4*)(f + 4);
  bf16x8 r;
  r[0] = (__bf16)a.x; r[1] = (__bf16)a.y; r[2] = (__bf16)a.z; r[3] = (__bf16)a.w;
  r[4] = (__bf16)b.x; r[5] = (__bf16)b.y; r[6] = (__bf16)b.z; r[7] = (__bf16)b.w;
  return r;
}

// ---------------- GEMM: C[m][n] = sum_k A[m][k]*Bt[n][k] + bias[n] --------------
// 128x128 tile, BK=32, 4 waves (2x2 of 64x64). Register staging.
// MODE 1: A = x (input dtype per flag). Scatter: Q->Qs*0.125 (B,H,S,D),
//         K->Kb (B,H,S,D), V->Vt (B,H,D,S). bias input dtype.
// MODE 2: A = attn out, head-major bf16 in Qs ((b*16+h)*2048+s)*64+dk.
//         C store in output dtype per flag. bias input dtype.
template <int MODE>
__global__ void gemm_bt(const void* A,
                        const bf16_t* __restrict__ Bt,
                        const void* __restrict__ bias,
                        void* C,
                        bf16_t* __restrict__ Qs,
                        bf16_t* __restrict__ Kb,
                        bf16_t* __restrict__ Vt,
                        int M, int N, int K,
                        const int* __restrict__ flagp) {
  const int isF32 = *flagp;
  __shared__ __align__(16) bf16_t As[128 * 32];
  __shared__ __align__(16) bf16_t Bs[128 * 32];

  const int tid = threadIdx.x;
  const int w = tid >> 6, lane = tid & 63;
  const int quad = lane >> 4, l16 = lane & 15;
  const int wm = w >> 1, wn = w & 1;
  const int m0 = blockIdx.y * 128, n0 = blockIdx.x * 128;

  const int srow = lane >> 2;          // 0..15 within a 16-row chunk
  const int scol = (lane & 3) * 8;     // k offset 0/8/16/24

  f32x4 acc[4][4];
#pragma unroll
  for (int i = 0; i < 4; ++i)
#pragma unroll
    for (int j = 0; j < 4; ++j) acc[i][j] = f32x4{0.f, 0.f, 0.f, 0.f};

  for (int k0 = 0; k0 < K; k0 += 32) {
    bf16x8 va[2], vb[2];
#pragma unroll
    for (int it = 0; it < 2; ++it) {
      const int chunk = w + it * 4;          // 8 chunks of 16 rows
      const int row = chunk * 16 + srow;
      const int m = m0 + row;
      if (MODE == 2) {
        // head-major gather (always bf16): b=m>>11, s=m&2047, h=k0>>6
        const size_t aoff =
            ((size_t)((m >> 11) * 16 + (k0 >> 6)) * 2048 + (m & 2047)) * 64 +
            (k0 & 63) + scol;
        va[it] = *(const bf16x8*)((const bf16_t*)A + aoff);
      } else {
        const size_t aoff = (size_t)m * K + (k0 + scol);
        va[it] = isF32 ? cvt8((const float*)A + aoff)
                       : *(const bf16x8*)((const bf16_t*)A + aoff);
      }
      vb[it] = *(const bf16x8*)(Bt + (size_t)(n0 + row) * K + (k0 + scol));
    }
    __syncthreads();  // previous iter's fragment reads done before overwriting LDS
#pragma unroll
    for (int it = 0; it < 2; ++it) {
      const int chunk = w + it * 4;
      *(bf16x8*)&As[chunk * 512 + lane * 8] = va[it];  // As[row*32+k]
      *(bf16x8*)&Bs[chunk * 512 + lane * 8] = vb[it];
    }
    __syncthreads();

    bf16x8 af[4], bfr[4];
#pragma unroll
    for (int i = 0; i < 4; ++i)
      af[i] = *(const bf16x8*)&As[(wm * 64 + i * 16 + l16) * 32 + quad * 8];
#pragma unroll
    for (int j = 0; j < 4; ++j)
      bfr[j] = *(const bf16x8*)&Bs[(wn * 64 + j * 16 + l16) * 32 + quad * 8];
#pragma unroll
    for (int i = 0; i < 4; ++i)
#pragma unroll
      for (int j = 0; j < 4; ++j) acc[i][j] = MFMA_BF16(af[i], bfr[j], acc[i][j]);
  }

  // epilogue — C/D layout: row = quad*4 + r, col = l16 (verified m89/m91)
#pragma unroll
  for (int j = 0; j < 4; ++j) {
    const int n = n0 + wn * 64 + j * 16 + l16;
    const float bj = isF32 ? ((const float*)bias)[n] : (float)((const bf16_t*)bias)[n];
#pragma unroll
    for (int i = 0; i < 4; ++i) {
      const int mbase = m0 + wm * 64 + i * 16 + quad * 4;
#pragma unroll
      for (int r = 0; r < 4; ++r) {
        const int m = mbase + r;
        const float v = acc[i][j][r] + bj;
        if (MODE == 2) {
          if (isF32) ((float*)C)[(size_t)m * N + n] = v;
          else       ((bf16_t*)C)[(size_t)m * N + n] = (bf16_t)v;
        } else {
          const int which = n >> 10;          // 0=Q 1=K 2=V
          const int e = n & 1023;
          const int h = e >> 6, d = e & 63;
          const int bb = m >> 11, s = m & 2047;
          const size_t bh = (size_t)(bb * 16 + h);
          if (which == 0)       Qs[(bh * 2048 + s) * 64 + d] = (bf16_t)(v * 0.125f);
          else if (which == 1)  Kb[(bh * 2048 + s) * 64 + d] = (bf16_t)v;
          else                  Vt[(bh * 64 + d) * 2048 + s] = (bf16_t)v;
        }
      }
    }
  }
}

// ---------------- causal flash attention (all-bf16 internal) ---------------------
// grid (qt=S/64, bh=B*H), block 256. Q pre-scaled; O written in place over this
// block's own Q rows (private -> race-free).
__global__ void attn_kernel(bf16_t* QO,
                            const bf16_t* __restrict__ Kb,
                            const bf16_t* __restrict__ Vt) {
  __shared__ __align__(16) bf16_t Ks[64 * 64];     // [key][d]
  __shared__ __align__(16) bf16_t Vs[64 * 64];     // [d][key]
  __shared__ __align__(16) bf16_t Ps[4][16 * 64];  // per-wave P, [q16][key64]

  const int qt = blockIdx.x;
  const int bh = blockIdx.y;
  const int tid = threadIdx.x, w = tid >> 6, lane = tid & 63;
  const int quad = lane >> 4, l16 = lane & 15;

  bf16_t* Q = QO + (size_t)bh * 2048 * 64;
  const bf16_t* K = Kb + (size_t)bh * 2048 * 64;
  const bf16_t* V = Vt + (size_t)bh * 64 * 2048;

  const int qrow = qt * 64 + w * 16;

  bf16x8 qf[2];
#pragma unroll
  for (int kk = 0; kk < 2; ++kk)
    qf[kk] = *(const bf16x8*)(Q + (size_t)(qrow + l16) * 64 + kk * 32 + quad * 8);

  f32x4 oacc[4];
  float mrow[4], lrow[4];
#pragma unroll
  for (int jd = 0; jd < 4; ++jd) oacc[jd] = f32x4{0.f, 0.f, 0.f, 0.f};
#pragma unroll
  for (int r = 0; r < 4; ++r) { mrow[r] = -1e30f; lrow[r] = 0.f; }

  const int srow8 = lane >> 3;
  const int scol8 = (lane & 7) * 8;

  for (int kt = 0; kt <= qt; ++kt) {
    bf16x8 kv[2], vv[2];
#pragma unroll
    for (int it = 0; it < 2; ++it) {
      const int chunk = w + it * 4;
      const int row = chunk * 8 + srow8;
      kv[it] = *(const bf16x8*)(K + (size_t)(kt * 64 + row) * 64 + scol8);
      vv[it] = *(const bf16x8*)(V + (size_t)row * 2048 + kt * 64 + scol8);
    }
    __syncthreads();
#pragma unroll
    for (int it = 0; it < 2; ++it) {
      const int chunk = w + it * 4;
      *(bf16x8*)&Ks[chunk * 512 + lane * 8] = kv[it];  // Ks[key*64+d]
      *(bf16x8*)&Vs[chunk * 512 + lane * 8] = vv[it];  // Vs[d*64+key]
    }
    __syncthreads();

    f32x4 s[4];
#pragma unroll
    for (int j = 0; j < 4; ++j) {
      const bf16x8 kf0 = *(const bf16x8*)&Ks[(j * 16 + l16) * 64 + quad * 8];
      const bf16x8 kf1 = *(const bf16x8*)&Ks[(j * 16 + l16) * 64 + 32 + quad * 8];
      f32x4 z = f32x4{0.f, 0.f, 0.f, 0.f};
      z = MFMA_BF16(qf[0], kf0, z);
      s[j] = MFMA_BF16(qf[1], kf1, z);
    }

    if (kt == qt) {
#pragma unroll
      for (int j = 0; j < 4; ++j) {
        const int key = kt * 64 + j * 16 + l16;
#pragma unroll
        for (int r = 0; r < 4; ++r) {
          const int q = qrow + quad * 4 + r;
          if (key > q) s[j][r] = -1e30f;
        }
      }
    }

#pragma unroll
    for (int r = 0; r < 4; ++r) {
      float mx = fmaxf(fmaxf(s[0][r], s[1][r]), fmaxf(s[2][r], s[3][r]));
#pragma unroll
      for (int off = 1; off < 16; off <<= 1) mx = fmaxf(mx, __shfl_xor(mx, off, 16));
      const float mnew = fmaxf(mrow[r], mx);
      const float alpha = __expf(mrow[r] - mnew);
      float ps = 0.f;
#pragma unroll
      for (int j = 0; j < 4; ++j) {
        const float p = __expf(s[j][r] - mnew);
        s[j][r] = p;
        ps += p;
      }
#pragma unroll
      for (int off = 1; off < 16; off <<= 1) ps += __shfl_xor(ps, off, 16);
      mrow[r] = mnew;
      lrow[r] = lrow[r] * alpha + ps;
#pragma unroll
      for (int jd = 0; jd < 4; ++jd) oacc[jd][r] *= alpha;
    }

#pragma unroll
    for (int j = 0; j < 4; ++j)
#pragma unroll
      for (int r = 0; r < 4; ++r)
        Ps[w][(quad * 4 + r) * 64 + j * 16 + l16] = (bf16_t)s[j][r];

    __syncthreads();

#pragma unroll
    for (int kk = 0; kk < 2; ++kk) {
      const bf16x8 pf = *(const bf16x8*)&Ps[w][l16 * 64 + kk * 32 + quad * 8];
#pragma unroll
      for (int jd = 0; jd < 4; ++jd) {
        const bf16x8 vf = *(const bf16x8*)&Vs[(jd * 16 + l16) * 64 + kk * 32 + quad * 8];
        oacc[jd] = MFMA_BF16(pf, vf, oacc[jd]);
      }
    }
  }

#pragma unroll
  for (int jd = 0; jd < 4; ++jd) {
    const int d = jd * 16 + l16;
#pragma unroll
    for (int r = 0; r < 4; ++r) {
      const int q = qrow + quad * 4 + r;
      const float v = oacc[jd][r] / fmaxf(lrow[r], 1e-30f);
      Q[(size_t)q * 64 + d] = (bf16_t)v;
    }
  }
}

// ---------------- launch ----------------------------------------------------------
extern "C" void kernel_launch(void* const* d_in, const int* in_sizes, int n_in,
                              void* d_out, int out_size, void* d_ws, size_t ws_size,
                              hipStream_t stream) {
  const void* x      = d_in[0];   // (2,2048,1024) f32 or bf16
  const void* W_attn = d_in[1];   // (1024,3072)
  const void* b_attn = d_in[2];   // (3072,)
  const void* W_proj = d_in[3];   // (1024,1024)
  const void* b_proj = d_in[4];   // (1024,)

  // ws: flag 256B + Qs 8MB + Kb 8MB + Wat 6MB + Wpt 2MB = 24MB. Vt lives in d_out.
  char* ws = (char*)d_ws;
  size_t off = 0;
  auto alloc = [&](size_t bytes) {
    char* p = ws + off;
    off += (bytes + 255) & ~(size_t)255;
    return p;
  };
  int*    flag = (int*)alloc(256);
  bf16_t* Qs   = (bf16_t*)alloc((size_t)32 * 2048 * 64 * 2);   // Q, then O in place
  bf16_t* Kb   = (bf16_t*)alloc((size_t)32 * 2048 * 64 * 2);
  bf16_t* Wat  = (bf16_t*)alloc((size_t)3072 * 1024 * 2);      // W_attn^T (N,K) bf16
  bf16_t* Wpt  = (bf16_t*)alloc((size_t)1024 * 1024 * 2);      // W_proj^T bf16
  bf16_t* Vt   = (bf16_t*)d_out;                               // (B,H,D,S), dead before proj

  detect_dtype<<<1, 256, 0, stream>>>((const unsigned short*)x, flag);

  transpose_any<<<dim3(3072 / 32, 1024 / 32), dim3(32, 8), 0, stream>>>(W_attn, Wat, 1024, 3072, flag);
  transpose_any<<<dim3(1024 / 32, 1024 / 32), dim3(32, 8), 0, stream>>>(W_proj, Wpt, 1024, 1024, flag);

  gemm_bt<1><<<dim3(3072 / 128, 4096 / 128), 256, 0, stream>>>(
      x, Wat, b_attn, nullptr, Qs, Kb, Vt, 4096, 3072, 1024, flag);

  attn_kernel<<<dim3(2048 / 64, 32), 256, 0, stream>>>(Qs, Kb, Vt);

  gemm_bt<2><<<dim3(1024 / 128, 4096 / 128), 256, 0, stream>>>(
      Qs, Wpt, b_proj, d_out, nullptr, nullptr, nullptr, 4096, 1024, 1024, flag);
}

// Round 5
// 301.980 us; speedup vs baseline: 1.0698x; 1.0698x over previous
//
#include <hip/hip_runtime.h>
#include <hip/hip_bf16.h>
#include <stdint.h>
#include <stddef.h>

typedef __bf16 bf16_t;
typedef __attribute__((ext_vector_type(8))) __bf16 bf16x8;   // 4 VGPRs, MFMA A/B operand
typedef __attribute__((ext_vector_type(4))) float f32x4;     // MFMA C/D

#define MFMA_BF16(a, b, c) __builtin_amdgcn_mfma_f32_16x16x32_bf16((a), (b), (c), 0, 0, 0)

// ---------------- dtype detector (inputs are f32 in practice; keep robust) ------
__global__ void detect_dtype(const unsigned short* __restrict__ x, int* __restrict__ flag) {
  __shared__ int cnt;
  if (threadIdx.x == 0) cnt = 0;
  __syncthreads();
  int local = 0;
  for (int i = threadIdx.x; i < 16384; i += 256) {
    const int e = (x[i] >> 7) & 0xFF;
    if (e >= 0x8D) local++;
  }
  atomicAdd(&cnt, local);
  __syncthreads();
  if (threadIdx.x == 0) *flag = (cnt > 16) ? 1 : 0;
}

// ---------------- transpose (any input dtype -> bf16): out[c][r] = in[r][c] ------
__global__ void transpose_any(const void* __restrict__ in, bf16_t* __restrict__ out,
                              int R, int C, const int* __restrict__ flagp) {
  const int isF32 = *flagp;
  __shared__ bf16_t tile[32][33];
  const int tx = threadIdx.x, ty = threadIdx.y;
  const int r0 = blockIdx.y * 32, c0 = blockIdx.x * 32;
#pragma unroll
  for (int i = 0; i < 4; ++i) {
    const size_t idx = (size_t)(r0 + ty + i * 8) * C + (c0 + tx);
    tile[ty + i * 8][tx] = isF32 ? (bf16_t)((const float*)in)[idx]
                                 : ((const bf16_t*)in)[idx];
  }
  __syncthreads();
#pragma unroll
  for (int i = 0; i < 4; ++i)
    out[(size_t)(c0 + ty + i * 8) * R + (r0 + tx)] = tile[tx][ty + i * 8];
}

__device__ __forceinline__ bf16x8 cvt8(const float* f) {
  const float4 a = *(const float4*)f, b = *(const float4*)(f + 4);
  bf16x8 r;
  r[0] = (__bf16)a.x; r[1] = (__bf16)a.y; r[2] = (__bf16)a.z; r[3] = (__bf16)a.w;
  r[4] = (__bf16)b.x; r[5] = (__bf16)b.y; r[6] = (__bf16)b.z; r[7] = (__bf16)b.w;
  return r;
}

// ---------------- GEMM: C[m][n] = sum_k A[m][k]*Bt[n][k] + bias[n] --------------
// 128x128 tile, BK=32, 4 waves. Register prefetch of next K-slice; LDS stride
// padded 32->40 elements (8-way -> 2-way bank conflicts).
#define GP 40  // padded LDS leading dim (elements)
template <int MODE>
__global__ void gemm_bt(const void* A,
                        const bf16_t* __restrict__ Bt,
                        const void* __restrict__ bias,
                        void* C,
                        bf16_t* __restrict__ Qs,
                        bf16_t* __restrict__ Kb,
                        bf16_t* __restrict__ Vt,
                        int M, int N, int K,
                        const int* __restrict__ flagp) {
  const int isF32 = *flagp;
  __shared__ __align__(16) bf16_t As[128 * GP];
  __shared__ __align__(16) bf16_t Bs[128 * GP];

  const int tid = threadIdx.x;
  const int w = tid >> 6, lane = tid & 63;
  const int quad = lane >> 4, l16 = lane & 15;
  const int wm = w >> 1, wn = w & 1;
  const int m0 = blockIdx.y * 128, n0 = blockIdx.x * 128;

  const int srow = lane >> 2;          // 0..15 within a 16-row chunk
  const int scol = (lane & 3) * 8;     // k offset 0/8/16/24

  auto loadA = [&](int k0, int it) -> bf16x8 {
    const int m = m0 + (w + it * 4) * 16 + srow;
    if (MODE == 2) {
      const size_t aoff =
          ((size_t)((m >> 11) * 16 + (k0 >> 6)) * 2048 + (m & 2047)) * 64 +
          (k0 & 63) + scol;
      return *(const bf16x8*)((const bf16_t*)A + aoff);
    }
    const size_t aoff = (size_t)m * K + (k0 + scol);
    return isF32 ? cvt8((const float*)A + aoff)
                 : *(const bf16x8*)((const bf16_t*)A + aoff);
  };
  auto loadB = [&](int k0, int it) -> bf16x8 {
    const int row = (w + it * 4) * 16 + srow;
    return *(const bf16x8*)(Bt + (size_t)(n0 + row) * K + (k0 + scol));
  };

  f32x4 acc[4][4];
#pragma unroll
  for (int i = 0; i < 4; ++i)
#pragma unroll
    for (int j = 0; j < 4; ++j) acc[i][j] = f32x4{0.f, 0.f, 0.f, 0.f};

  bf16x8 va[2], vb[2];
#pragma unroll
  for (int it = 0; it < 2; ++it) { va[it] = loadA(0, it); vb[it] = loadB(0, it); }

  for (int k0 = 0; k0 < K; k0 += 32) {
    __syncthreads();  // previous iter's fragment reads done before overwriting LDS
#pragma unroll
    for (int it = 0; it < 2; ++it) {
      const int chunk = w + it * 4;
      *(bf16x8*)&As[(chunk * 16 + srow) * GP + scol] = va[it];
      *(bf16x8*)&Bs[(chunk * 16 + srow) * GP + scol] = vb[it];
    }
    __syncthreads();

    // prefetch next K-slice into regs; completes during MFMA below
    if (k0 + 32 < K) {
#pragma unroll
      for (int it = 0; it < 2; ++it) {
        va[it] = loadA(k0 + 32, it);
        vb[it] = loadB(k0 + 32, it);
      }
    }

    bf16x8 af[4], bfr[4];
#pragma unroll
    for (int i = 0; i < 4; ++i)
      af[i] = *(const bf16x8*)&As[(wm * 64 + i * 16 + l16) * GP + quad * 8];
#pragma unroll
    for (int j = 0; j < 4; ++j)
      bfr[j] = *(const bf16x8*)&Bs[(wn * 64 + j * 16 + l16) * GP + quad * 8];
#pragma unroll
    for (int i = 0; i < 4; ++i)
#pragma unroll
      for (int j = 0; j < 4; ++j) acc[i][j] = MFMA_BF16(af[i], bfr[j], acc[i][j]);
  }

  // epilogue — C/D layout: row = quad*4 + r, col = l16
#pragma unroll
  for (int j = 0; j < 4; ++j) {
    const int n = n0 + wn * 64 + j * 16 + l16;
    const float bj = isF32 ? ((const float*)bias)[n] : (float)((const bf16_t*)bias)[n];
#pragma unroll
    for (int i = 0; i < 4; ++i) {
      const int mbase = m0 + wm * 64 + i * 16 + quad * 4;
#pragma unroll
      for (int r = 0; r < 4; ++r) {
        const int m = mbase + r;
        const float v = acc[i][j][r] + bj;
        if (MODE == 2) {
          if (isF32) ((float*)C)[(size_t)m * N + n] = v;
          else       ((bf16_t*)C)[(size_t)m * N + n] = (bf16_t)v;
        } else {
          const int which = n >> 10;          // 0=Q 1=K 2=V
          const int e = n & 1023;
          const int h = e >> 6, d = e & 63;
          const int bb = m >> 11, s = m & 2047;
          const size_t bh = (size_t)(bb * 16 + h);
          if (which == 0)       Qs[(bh * 2048 + s) * 64 + d] = (bf16_t)(v * 0.125f);
          else if (which == 1)  Kb[(bh * 2048 + s) * 64 + d] = (bf16_t)v;
          else                  Vt[(bh * 64 + d) * 2048 + s] = (bf16_t)v;
        }
      }
    }
  }
}

// ---------------- causal flash attention -----------------------------------------
// grid (qt, bh), block 256. qt REVERSED (longest blocks first). Register prefetch
// of next K/V tile; LDS stride padded 64->72 (16-way -> 2-way read conflicts).
#define AP 72
__global__ void attn_kernel(bf16_t* QO,
                            const bf16_t* __restrict__ Kb,
                            const bf16_t* __restrict__ Vt) {
  __shared__ __align__(16) bf16_t Ks[64 * AP];     // [key][d]
  __shared__ __align__(16) bf16_t Vs[64 * AP];     // [d][key]
  __shared__ __align__(16) bf16_t Ps[4][16 * AP];  // per-wave P, [q16][key64]

  const int qt = gridDim.x - 1 - blockIdx.x;       // longest first
  const int bh = blockIdx.y;
  const int tid = threadIdx.x, w = tid >> 6, lane = tid & 63;
  const int quad = lane >> 4, l16 = lane & 15;

  bf16_t* Q = QO + (size_t)bh * 2048 * 64;
  const bf16_t* K = Kb + (size_t)bh * 2048 * 64;
  const bf16_t* V = Vt + (size_t)bh * 64 * 2048;

  const int qrow = qt * 64 + w * 16;

  bf16x8 qf[2];
#pragma unroll
  for (int kk = 0; kk < 2; ++kk)
    qf[kk] = *(const bf16x8*)(Q + (size_t)(qrow + l16) * 64 + kk * 32 + quad * 8);

  f32x4 oacc[4];
  float mrow[4], lrow[4];
#pragma unroll
  for (int jd = 0; jd < 4; ++jd) oacc[jd] = f32x4{0.f, 0.f, 0.f, 0.f};
#pragma unroll
  for (int r = 0; r < 4; ++r) { mrow[r] = -1e30f; lrow[r] = 0.f; }

  const int srow8 = lane >> 3;         // 0..7
  const int scol8 = (lane & 7) * 8;    // 0..56

  auto loadK = [&](int kt, int it) -> bf16x8 {
    const int row = (w + it * 4) * 8 + srow8;
    return *(const bf16x8*)(K + (size_t)(kt * 64 + row) * 64 + scol8);
  };
  auto loadV = [&](int kt, int it) -> bf16x8 {
    const int row = (w + it * 4) * 8 + srow8;
    return *(const bf16x8*)(V + (size_t)row * 2048 + kt * 64 + scol8);
  };

  bf16x8 kv[2], vv[2];
#pragma unroll
  for (int it = 0; it < 2; ++it) { kv[it] = loadK(0, it); vv[it] = loadV(0, it); }

  for (int kt = 0; kt <= qt; ++kt) {
    __syncthreads();  // previous iter's Ks/Vs fragment reads done
#pragma unroll
    for (int it = 0; it < 2; ++it) {
      const int chunk = w + it * 4;
      const int row = chunk * 8 + srow8;
      *(bf16x8*)&Ks[row * AP + scol8] = kv[it];  // Ks[key][d]
      *(bf16x8*)&Vs[row * AP + scol8] = vv[it];  // Vs[d][key]
    }
    __syncthreads();

    // prefetch next tile; completes during QK/softmax/PV below
    if (kt < qt) {
#pragma unroll
      for (int it = 0; it < 2; ++it) { kv[it] = loadK(kt + 1, it); vv[it] = loadV(kt + 1, it); }
    }

    // S = Q K^T (Q pre-scaled by 1/8)
    f32x4 s[4];
#pragma unroll
    for (int j = 0; j < 4; ++j) {
      const bf16x8 kf0 = *(const bf16x8*)&Ks[(j * 16 + l16) * AP + quad * 8];
      const bf16x8 kf1 = *(const bf16x8*)&Ks[(j * 16 + l16) * AP + 32 + quad * 8];
      f32x4 z = f32x4{0.f, 0.f, 0.f, 0.f};
      z = MFMA_BF16(qf[0], kf0, z);
      s[j] = MFMA_BF16(qf[1], kf1, z);
    }

    if (kt == qt) {  // diagonal tile: causal mask (wave-uniform branch)
#pragma unroll
      for (int j = 0; j < 4; ++j) {
        const int key = kt * 64 + j * 16 + l16;
#pragma unroll
        for (int r = 0; r < 4; ++r) {
          const int q = qrow + quad * 4 + r;
          if (key > q) s[j][r] = -1e30f;
        }
      }
    }

    // online softmax; row r lives on the 16 lanes of this quad group
#pragma unroll
    for (int r = 0; r < 4; ++r) {
      float mx = fmaxf(fmaxf(s[0][r], s[1][r]), fmaxf(s[2][r], s[3][r]));
#pragma unroll
      for (int off = 1; off < 16; off <<= 1) mx = fmaxf(mx, __shfl_xor(mx, off, 16));
      const float mnew = fmaxf(mrow[r], mx);
      const float alpha = __expf(mrow[r] - mnew);
      float ps = 0.f;
#pragma unroll
      for (int j = 0; j < 4; ++j) {
        const float p = __expf(s[j][r] - mnew);
        s[j][r] = p;
        ps += p;
      }
#pragma unroll
      for (int off = 1; off < 16; off <<= 1) ps += __shfl_xor(ps, off, 16);
      mrow[r] = mnew;
      lrow[r] = lrow[r] * alpha + ps;
#pragma unroll
      for (int jd = 0; jd < 4; ++jd) oacc[jd][r] *= alpha;
    }

    // P: C/D layout -> LDS -> A-operand layout
#pragma unroll
    for (int j = 0; j < 4; ++j)
#pragma unroll
      for (int r = 0; r < 4; ++r)
        Ps[w][(quad * 4 + r) * AP + j * 16 + l16] = (bf16_t)s[j][r];

    __syncthreads();  // also separates Ps write/read across the block

#pragma unroll
    for (int kk = 0; kk < 2; ++kk) {
      const bf16x8 pf = *(const bf16x8*)&Ps[w][l16 * AP + kk * 32 + quad * 8];
#pragma unroll
      for (int jd = 0; jd < 4; ++jd) {
        const bf16x8 vf = *(const bf16x8*)&Vs[(jd * 16 + l16) * AP + kk * 32 + quad * 8];
        oacc[jd] = MFMA_BF16(pf, vf, oacc[jd]);
      }
    }
  }

  // O /= l, write in place over this block's own Q rows (private -> race-free)
#pragma unroll
  for (int jd = 0; jd < 4; ++jd) {
    const int d = jd * 16 + l16;
#pragma unroll
    for (int r = 0; r < 4; ++r) {
      const int q = qrow + quad * 4 + r;
      const float v = oacc[jd][r] / fmaxf(lrow[r], 1e-30f);
      Q[(size_t)q * 64 + d] = (bf16_t)v;
    }
  }
}

// ---------------- launch ----------------------------------------------------------
extern "C" void kernel_launch(void* const* d_in, const int* in_sizes, int n_in,
                              void* d_out, int out_size, void* d_ws, size_t ws_size,
                              hipStream_t stream) {
  const void* x      = d_in[0];   // (2,2048,1024)
  const void* W_attn = d_in[1];   // (1024,3072)
  const void* b_attn = d_in[2];   // (3072,)
  const void* W_proj = d_in[3];   // (1024,1024)
  const void* b_proj = d_in[4];   // (1024,)

  // ws: flag 256B + Qs 8MB + Kb 8MB + Wat 6MB + Wpt 2MB = 24MB. Vt lives in d_out.
  char* ws = (char*)d_ws;
  size_t off = 0;
  auto alloc = [&](size_t bytes) {
    char* p = ws + off;
    off += (bytes + 255) & ~(size_t)255;
    return p;
  };
  int*    flag = (int*)alloc(256);
  bf16_t* Qs   = (bf16_t*)alloc((size_t)32 * 2048 * 64 * 2);   // Q, then O in place
  bf16_t* Kb   = (bf16_t*)alloc((size_t)32 * 2048 * 64 * 2);
  bf16_t* Wat  = (bf16_t*)alloc((size_t)3072 * 1024 * 2);      // W_attn^T (N,K) bf16
  bf16_t* Wpt  = (bf16_t*)alloc((size_t)1024 * 1024 * 2);      // W_proj^T bf16
  bf16_t* Vt   = (bf16_t*)d_out;                               // (B,H,D,S), dead before proj

  detect_dtype<<<1, 256, 0, stream>>>((const unsigned short*)x, flag);

  transpose_any<<<dim3(3072 / 32, 1024 / 32), dim3(32, 8), 0, stream>>>(W_attn, Wat, 1024, 3072, flag);
  transpose_any<<<dim3(1024 / 32, 1024 / 32), dim3(32, 8), 0, stream>>>(W_proj, Wpt, 1024, 1024, flag);

  gemm_bt<1><<<dim3(3072 / 128, 4096 / 128), 256, 0, stream>>>(
      x, Wat, b_attn, nullptr, Qs, Kb, Vt, 4096, 3072, 1024, flag);

  attn_kernel<<<dim3(2048 / 64, 32), 256, 0, stream>>>(Qs, Kb, Vt);

  gemm_bt<2><<<dim3(1024 / 128, 4096 / 128), 256, 0, stream>>>(
      Qs, Wpt, b_proj, d_out, nullptr, nullptr, nullptr, 4096, 1024, 1024, flag);
}